// Round 10
// baseline (484.833 us; speedup 1.0000x reference)
//
#include <hip/hip_runtime.h>
#include <hip/hip_bf16.h>

#define S_LEN 2048
#define NHEAD 16
#define DHEAD 64
#define EMB   1024
#define KBLK  64
#define NT    (S_LEN / KBLK)   // 32

typedef short s16x8 __attribute__((ext_vector_type(8)));
typedef float f32x4 __attribute__((ext_vector_type(4)));

#define MFMA16(a, b, c) __builtin_amdgcn_mfma_f32_16x16x32_bf16(a, b, c, 0, 0, 0)

#if __has_builtin(__builtin_amdgcn_exp2f)
#define EXP2(x) __builtin_amdgcn_exp2f(x)
#else
#define EXP2(x) exp2f(x)
#endif

__device__ inline unsigned short f2bf(float f) {
    return __builtin_bit_cast(unsigned short, __float2bfloat16(f));
}

__device__ inline s16x8 cvt8(const float* __restrict__ p) {
    const f32x4* q = (const f32x4*)p;
    f32x4 a = q[0], b = q[1];
    s16x8 r;
    r[0] = (short)f2bf(a[0]); r[1] = (short)f2bf(a[1]);
    r[2] = (short)f2bf(a[2]); r[3] = (short)f2bf(a[3]);
    r[4] = (short)f2bf(b[0]); r[5] = (short)f2bf(b[1]);
    r[6] = (short)f2bf(b[2]); r[7] = (short)f2bf(b[3]);
    return r;
}

// K0: all weight f32->bf16 conversions in one launch.
// blocks [0,1024): Wo ; [1024,1028): Wq ; [1028,1032): Wk ; [1032,1036): Wv
__global__ __launch_bounds__(256) void cvt_weights(const float* __restrict__ Wo,
                                                   const float* __restrict__ Wq,
                                                   const float* __restrict__ Wk,
                                                   const float* __restrict__ Wv,
                                                   unsigned short* __restrict__ Wb,
                                                   unsigned short* __restrict__ Wq3,
                                                   unsigned short* __restrict__ Wk3,
                                                   unsigned short* __restrict__ Wv3) {
    int bid = blockIdx.x;
    const float* src; unsigned short* dst; int base;
    if (bid < 1024)      { src = Wo; dst = Wb;  base = bid; }
    else if (bid < 1028) { src = Wq; dst = Wq3; base = bid - 1024; }
    else if (bid < 1032) { src = Wk; dst = Wk3; base = bid - 1028; }
    else                 { src = Wv; dst = Wv3; base = bid - 1032; }
    int i = (base * 256 + threadIdx.x) * 4;
    f32x4 v = *(const f32x4*)(src + i);
    unsigned long long pk = (unsigned long long)f2bf(v[0])
                          | ((unsigned long long)f2bf(v[1]) << 16)
                          | ((unsigned long long)f2bf(v[2]) << 32)
                          | ((unsigned long long)f2bf(v[3]) << 48);
    *(unsigned long long*)(dst + i) = pk;
}

// K1: fused projections + mask packing. blockIdx.y selects mode:
//   0: Q-proj (scaled), 1: K-proj, 2: V-proj (transposed), 3: packmask.
// All four run concurrently in one launch (independent outputs).
__global__ __launch_bounds__(256) void proj4(const float* __restrict__ q_in,
                                             const float* __restrict__ k_in,
                                             const float* __restrict__ v_in,
                                             const int* __restrict__ mask,
                                             const unsigned short* __restrict__ Wq3,
                                             const unsigned short* __restrict__ Wk3,
                                             const unsigned short* __restrict__ Wv3,
                                             unsigned short* __restrict__ Qp,
                                             unsigned short* __restrict__ Kp,
                                             unsigned short* __restrict__ Vt,
                                             unsigned long long* __restrict__ Mp,
                                             float qscale) {
    int mode = blockIdx.y;
    int wave = threadIdx.x >> 6, lane = threadIdx.x & 63;
    int bid = blockIdx.x;

    if (mode == 3) {   // packmask: 2048 blocks x 4 waves x 32 words = 262144
        int wid0 = (bid * 4 + wave) * 32;
        #pragma unroll 8
        for (int i = 0; i < 32; ++i) {
            size_t w = (size_t)wid0 + i;
            int m = mask[w * 64 + lane];
            unsigned long long bal = __ballot(m != 0);
            if (lane == 0) Mp[w] = bal;
        }
        return;
    }

    int g = lane >> 4, c = lane & 15;
    const f32x4 fzero = {0.f, 0.f, 0.f, 0.f};

    if (mode == 2) {   // V projection, transposed output: Vt[(bh*64+e)*S + s]
        int sblk = bid & 31, bh = bid >> 5;
        int s0 = sblk * 64;
        int b = bh >> 4, h = bh & 15;
        int m0 = wave * 16;

        s16x8 a0 = *(const s16x8*)(Wv3 + (size_t)(m0 + c) * 64 + g * 8);
        s16x8 a1 = *(const s16x8*)(Wv3 + (size_t)(m0 + c) * 64 + 32 + g * 8);

        f32x4 acc[4];
        #pragma unroll
        for (int nt = 0; nt < 4; ++nt) {
            int s = s0 + nt * 16 + c;
            const float* xr = v_in + ((size_t)(b * S_LEN + s) * NHEAD + h) * DHEAD;
            s16x8 b0 = cvt8(xr + g * 8);
            s16x8 b1 = cvt8(xr + 32 + g * 8);
            f32x4 z = fzero;
            z = MFMA16(a0, b0, z);
            z = MFMA16(a1, b1, z);
            acc[nt] = z;
        }
        #pragma unroll
        for (int j = 0; j < 4; ++j) {
            int e = m0 + g * 4 + j;
            unsigned short* Vr = Vt + ((size_t)(bh * DHEAD) + e) * S_LEN;
            #pragma unroll
            for (int nt = 0; nt < 4; ++nt)
                Vr[s0 + nt * 16 + c] = f2bf(acc[nt][j]);
        }
        return;
    }

    // mode 0/1: Q/K projection
    const float* x = (mode == 0) ? q_in : k_in;
    const unsigned short* W3 = (mode == 0) ? Wq3 : Wk3;
    unsigned short* out = (mode == 0) ? Qp : Kp;
    float scale = (mode == 0) ? qscale : 1.0f;

    int m0 = (bid * 4 + wave) * 16;
    s16x8 a0 = cvt8(x + (size_t)(m0 + c) * 64 + g * 8);
    s16x8 a1 = cvt8(x + (size_t)(m0 + c) * 64 + 32 + g * 8);

    f32x4 acc[4];
    #pragma unroll
    for (int nt = 0; nt < 4; ++nt) {
        s16x8 b0 = *(const s16x8*)(W3 + (size_t)(nt * 16 + c) * 64 + g * 8);
        s16x8 b1 = *(const s16x8*)(W3 + (size_t)(nt * 16 + c) * 64 + 32 + g * 8);
        f32x4 z = fzero;
        z = MFMA16(a0, b0, z);
        z = MFMA16(a1, b1, z);
        acc[nt] = z;
    }
    #pragma unroll
    for (int j = 0; j < 4; ++j) {
        int m = m0 + g * 4 + j;
        int h = m & 15, s = (m >> 4) & (S_LEN - 1), b = m >> 15;
        #pragma unroll
        for (int nt = 0; nt < 4; ++nt) {
            int col = nt * 16 + c;
            out[((size_t)((b * NHEAD + h) * S_LEN + s)) * DHEAD + col] = f2bf(acc[nt][j] * scale);
        }
    }
}

// K2: flash attention. 1024 blocks XCD-grouped; Q-tile 128/block, 32 q-rows/wave.
// K/V LDS tiles stored in fragment order with 16B-slot XOR swizzle
//   phys16 = (sub*64 + pos) ^ ((ch>>1)&3)    [applied on BOTH write & read, rule #21]
// P buffer: per-wave 16x64, XOR swizzle phys16 = (r*8 + chunk) ^ (r&7).
// LDS total 40960 B -> 4 blocks/CU.
__global__ __launch_bounds__(256, 4) void attn(const unsigned short* __restrict__ Qp,
                                               const unsigned short* __restrict__ Kp,
                                               const unsigned short* __restrict__ Vt,
                                               const unsigned long long* __restrict__ Mp,
                                               unsigned short* __restrict__ Oa) {
    __shared__ unsigned short Kl[2][4096];   // 8 KiB per buf
    __shared__ unsigned short Vl[2][4096];
    __shared__ unsigned short Pl[4][1024];   // 2 KiB per wave

    int tid = threadIdx.x;
    int wave = tid >> 6, lane = tid & 63, g = lane >> 4, c = lane & 15;
    int bid = blockIdx.x;
    int xcd = bid & 7, idx = bid >> 3;       // bijective: 1024 % 8 == 0
    int bh = xcd * 8 + (idx >> 4);
    int qblk = idx & 15;
    int b = bh >> 4, h = bh & 15;
    int q0 = qblk * 128 + wave * 32;

    const unsigned short* Qb = Qp + (size_t)bh * S_LEN * DHEAD;
    const unsigned short* Kb = Kp + (size_t)bh * S_LEN * DHEAD;
    const unsigned short* Vb = Vt + (size_t)bh * DHEAD * S_LEN;
    const unsigned long long* mb = Mp + (size_t)b * S_LEN * NT;

    s16x8 aq[2][2];
    #pragma unroll
    for (int mi = 0; mi < 2; ++mi) {
        aq[mi][0] = *(const s16x8*)(Qb + (size_t)(q0 + mi * 16 + c) * 64 + g * 8);
        aq[mi][1] = *(const s16x8*)(Qb + (size_t)(q0 + mi * 16 + c) * 64 + 32 + g * 8);
    }

    // staging: thread owns chunks {2t, 2t+1}; chunk=(row kr, 16B-col ch)
    int kr = tid >> 2;
    int kch0 = (tid & 3) * 2, kch1 = kch0 + 1;
    const unsigned short* Ksrc = Kb + (size_t)kr * 64 + kch0 * 8;
    const unsigned short* Vsrc = Vb + (size_t)kr * S_LEN + kch0 * 8;
    // swizzled LDS write offsets (shorts)
    int o0 = ((((kr >> 4) * 2 + (kch0 >> 2)) * 64 + (kch0 & 3) * 16 + (kr & 15)) ^ ((kch0 >> 1) & 3)) * 8;
    int o1 = ((((kr >> 4) * 2 + (kch1 >> 2)) * 64 + (kch1 & 3) * 16 + (kr & 15)) ^ ((kch1 >> 1) & 3)) * 8;
    // swizzled LDS read offsets (shorts): ro[nt][kh]
    int ro[4][2];
    #pragma unroll
    for (int nt = 0; nt < 4; ++nt)
        #pragma unroll
        for (int kh = 0; kh < 2; ++kh)
            ro[nt][kh] = (((nt * 2 + kh) * 64 + lane) ^ ((kh * 2 + (g >> 1)) & 3)) * 8;
    // P read offsets
    int po0 = ((c * 8 + g) ^ (c & 7)) * 8;
    int po1 = ((c * 8 + g + 4) ^ (c & 7)) * 8;

    const f32x4 fzero = {0.f, 0.f, 0.f, 0.f};
    f32x4 acc[2][4], accl[2];
    #pragma unroll
    for (int mi = 0; mi < 2; ++mi) {
        accl[mi] = fzero;
        #pragma unroll
        for (int nt = 0; nt < 4; ++nt) acc[mi][nt] = fzero;
    }
    s16x8 ones;
    #pragma unroll
    for (int i = 0; i < 8; ++i) ones[i] = (short)0x3F80;   // bf16 1.0

    unsigned short* Pw = Pl[wave];

    s16x8 gk0, gk1, gv0, gv1;
    auto LOADR = [&](int kt) {
        size_t k0 = (size_t)kt * KBLK;
        gk0 = *(const s16x8*)(Ksrc + k0 * 64);
        gk1 = *(const s16x8*)(Ksrc + k0 * 64 + 8);
        gv0 = *(const s16x8*)(Vsrc + k0);
        gv1 = *(const s16x8*)(Vsrc + k0 + 8);
    };
    auto STAGEW = [&](int bufv) {
        *(s16x8*)(&Kl[bufv][o0]) = gk0;
        *(s16x8*)(&Kl[bufv][o1]) = gk1;
        *(s16x8*)(&Vl[bufv][o0]) = gv0;
        *(s16x8*)(&Vl[bufv][o1]) = gv1;
    };

    auto COMPUTE = [&](int bufv, int kt) {
        unsigned long long mw[2][4];
        #pragma unroll
        for (int mi = 0; mi < 2; ++mi)
            #pragma unroll
            for (int j = 0; j < 4; ++j)
                mw[mi][j] = mb[(size_t)(q0 + mi * 16 + g * 4 + j) * NT + kt];

        f32x4 sc[2][4];
        #pragma unroll
        for (int nt = 0; nt < 4; ++nt) {
            s16x8 kf0 = *(const s16x8*)(&Kl[bufv][ro[nt][0]]);
            s16x8 kf1 = *(const s16x8*)(&Kl[bufv][ro[nt][1]]);
            #pragma unroll
            for (int mi = 0; mi < 2; ++mi) {
                f32x4 z = MFMA16(aq[mi][0], kf0, fzero);
                sc[mi][nt] = MFMA16(aq[mi][1], kf1, z);
            }
        }
        // softmax numerator + transpose via per-wave swizzled P buffer (reused per mi)
        s16x8 ap[2][2];
        #pragma unroll
        for (int mi = 0; mi < 2; ++mi) {
            #pragma unroll
            for (int j = 0; j < 4; ++j) {
                unsigned wlo = (unsigned)mw[mi][j];
                unsigned whi = (unsigned)(mw[mi][j] >> 32);
                int r = g * 4 + j;
                int rb = r * 8, rx = r & 7;
                #pragma unroll
                for (int nt = 0; nt < 4; ++nt) {
                    float e = EXP2(sc[mi][nt][j]);
                    unsigned part = (nt < 2) ? wlo : whi;
                    float p = e * (float)((part >> ((nt & 1) * 16 + c)) & 1u);
                    int ph = (rb + nt * 2 + (c >> 3)) ^ rx;
                    Pw[ph * 8 + (c & 7)] = f2bf(p);
                }
            }
            ap[mi][0] = *(const s16x8*)(Pw + po0);   // same-wave DS in-order
            ap[mi][1] = *(const s16x8*)(Pw + po1);
            accl[mi] = MFMA16(ap[mi][0], ones, accl[mi]);
            accl[mi] = MFMA16(ap[mi][1], ones, accl[mi]);
        }
        #pragma unroll
        for (int nt = 0; nt < 4; ++nt) {
            s16x8 vf0 = *(const s16x8*)(&Vl[bufv][ro[nt][0]]);
            s16x8 vf1 = *(const s16x8*)(&Vl[bufv][ro[nt][1]]);
            #pragma unroll
            for (int mi = 0; mi < 2; ++mi) {
                acc[mi][nt] = MFMA16(ap[mi][0], vf0, acc[mi][nt]);
                acc[mi][nt] = MFMA16(ap[mi][1], vf1, acc[mi][nt]);
            }
        }
    };

    LOADR(0);
    STAGEW(0);
    __syncthreads();
    for (int kt = 0; kt < NT; ++kt) {
        int cur = kt & 1;
        if (kt + 1 < NT) LOADR(kt + 1);
        COMPUTE(cur, kt);
        __syncthreads();
        if (kt + 1 < NT) {
            STAGEW(cur ^ 1);
            __syncthreads();
        }
    }

    #pragma unroll
    for (int mi = 0; mi < 2; ++mi)
        #pragma unroll
        for (int j = 0; j < 4; ++j) {
            int q = q0 + mi * 16 + g * 4 + j;
            float inv = 1.f / accl[mi][j];
            #pragma unroll
            for (int nt = 0; nt < 4; ++nt)
                Oa[((size_t)(b * S_LEN + q)) * EMB + h * DHEAD + nt * 16 + c] = f2bf(acc[mi][nt][j] * inv);
        }
}

// K3: out = Oa(8192x1024,bf16) @ Wo^T + bo. Flat 512 grid, XCD-grouped by row-panel.
__global__ __launch_bounds__(256, 2) void outproj(const unsigned short* __restrict__ A,
                                                  const unsigned short* __restrict__ Wb,
                                                  const float* __restrict__ bo,
                                                  float* __restrict__ out) {
    int wave = threadIdx.x >> 6, lane = threadIdx.x & 63;
    int g = lane >> 4, c = lane & 15;
    int bid = blockIdx.x;
    int xcd = bid & 7, idx = bid >> 3;
    int bx = xcd * 4 + (idx >> 4);
    int by = idx & 15;
    int r0 = bx * 256 + wave * 64;
    int n0 = by * 64;

    float bias[4];
    #pragma unroll
    for (int nt = 0; nt < 4; ++nt) bias[nt] = bo[n0 + nt * 16 + c];

    const f32x4 fzero = {0.f, 0.f, 0.f, 0.f};
    f32x4 acc[4][4];
    #pragma unroll
    for (int mi = 0; mi < 4; ++mi)
        #pragma unroll
        for (int nt = 0; nt < 4; ++nt) acc[mi][nt] = fzero;

    s16x8 aA[4], bA[4], aB[4], bB[4];
    auto LOADT = [&](s16x8 (&a)[4], s16x8 (&bw)[4], int kt) {
        int kb = kt * 32;
        #pragma unroll
        for (int mi = 0; mi < 4; ++mi)
            a[mi] = *(const s16x8*)(A + (size_t)(r0 + mi * 16 + c) * EMB + kb + g * 8);
        #pragma unroll
        for (int nt = 0; nt < 4; ++nt)
            bw[nt] = *(const s16x8*)(Wb + (size_t)(n0 + nt * 16 + c) * EMB + kb + g * 8);
    };
    auto MM = [&](s16x8 (&a)[4], s16x8 (&bw)[4]) {
        #pragma unroll
        for (int mi = 0; mi < 4; ++mi)
            #pragma unroll
            for (int nt = 0; nt < 4; ++nt)
                acc[mi][nt] = MFMA16(a[mi], bw[nt], acc[mi][nt]);
    };

    LOADT(aA, bA, 0);
    for (int kt = 0; kt < EMB / 32; kt += 2) {
        LOADT(aB, bB, kt + 1);
        MM(aA, bA);
        if (kt + 2 < EMB / 32) LOADT(aA, bA, kt + 2);
        MM(aB, bB);
    }

    #pragma unroll
    for (int mi = 0; mi < 4; ++mi)
        #pragma unroll
        for (int j = 0; j < 4; ++j) {
            int row = r0 + mi * 16 + g * 4 + j;
            #pragma unroll
            for (int nt = 0; nt < 4; ++nt)
                out[(size_t)row * EMB + n0 + nt * 16 + c] = acc[mi][nt][j] + bias[nt];
        }
}

extern "C" void kernel_launch(void* const* d_in, const int* in_sizes, int n_in,
                              void* d_out, int out_size, void* d_ws, size_t ws_size,
                              hipStream_t stream) {
    (void)in_sizes; (void)n_in; (void)out_size; (void)ws_size;
    const float* values  = (const float*)d_in[0];
    const float* keys    = (const float*)d_in[1];
    const float* queries = (const float*)d_in[2];
    const int*   mask    = (const int*)d_in[3];
    const float* Wv = (const float*)d_in[4];
    const float* Wk = (const float*)d_in[5];
    const float* Wq = (const float*)d_in[6];
    const float* Wo = (const float*)d_in[7];
    const float* bo = (const float*)d_in[8];
    float* out = (float*)d_out;

    unsigned short* Qp = (unsigned short*)d_ws;
    unsigned short* Kp = Qp + (size_t)8 * 1024 * 1024;
    unsigned short* Vt = Kp + (size_t)8 * 1024 * 1024;
    unsigned short* Oa = Vt + (size_t)8 * 1024 * 1024;
    unsigned short* Wb = Oa + (size_t)8 * 1024 * 1024;
    unsigned long long* Mp = (unsigned long long*)(Wb + (size_t)1024 * 1024);
    unsigned short* Wq3 = (unsigned short*)(Mp + (size_t)262144);
    unsigned short* Wk3 = Wq3 + 4096;
    unsigned short* Wv3 = Wk3 + 4096;

    const float QSCALE = 0.045084220027780106f;   // log2(e) / sqrt(1024)

    cvt_weights<<<1036, 256, 0, stream>>>(Wo, Wq, Wk, Wv, Wb, Wq3, Wk3, Wv3);
    proj4<<<dim3(2048, 4), 256, 0, stream>>>(queries, keys, values, mask,
                                             Wq3, Wk3, Wv3, Qp, Kp, Vt, Mp, QSCALE);
    attn<<<1024, 256, 0, stream>>>(Qp, Kp, Vt, Mp, Oa);
    outproj<<<512, 256, 0, stream>>>(Oa, Wb, bo, out);
}